// Round 2
// baseline (394.010 us; speedup 1.0000x reference)
//
#include <hip/hip_runtime.h>
#include <hip/hip_bf16.h>
#include <math.h>

typedef __bf16 bf16_t;
typedef bf16_t bf16x8 __attribute__((ext_vector_type(8)));
typedef bf16_t bf16x4v __attribute__((ext_vector_type(4)));
typedef float f32x4 __attribute__((ext_vector_type(4)));

#define S_LEN 2048
#define HDIM 2048
#define QKV_LD 3072

// ---------------- cast fp32 -> bf16 (vectorized) ----------------
__global__ __launch_bounds__(256) void cast_bf16_kernel(const float* __restrict__ in,
                                                        bf16_t* __restrict__ out, int n4) {
  int i = blockIdx.x * 256 + threadIdx.x;
  if (i >= n4) return;
  float4 v = ((const float4*)in)[i];
  bf16x4v o;
  o[0] = (bf16_t)v.x; o[1] = (bf16_t)v.y; o[2] = (bf16_t)v.z; o[3] = (bf16_t)v.w;
  ((bf16x4v*)out)[i] = o;
}

// ---------------- transpose + cast: in (K x N) fp32 -> out (N x K) bf16 ----------------
__global__ __launch_bounds__(256) void transpose_cast_kernel(const float* __restrict__ in,
                                                             bf16_t* __restrict__ out,
                                                             int K, int N) {
  __shared__ float tile[32][33];
  int n0 = blockIdx.x * 32, k0 = blockIdx.y * 32;
  int tx = threadIdx.x & 31, ty = threadIdx.x >> 5;
#pragma unroll
  for (int i = 0; i < 4; ++i)
    tile[ty + i * 8][tx] = in[(size_t)(k0 + ty + i * 8) * N + n0 + tx];
  __syncthreads();
#pragma unroll
  for (int i = 0; i < 4; ++i)
    out[(size_t)(n0 + ty + i * 8) * K + k0 + tx] = (bf16_t)tile[tx][ty + i * 8];
}

// ---------------- block reduction helper (blockDim == 256) ----------------
__device__ __forceinline__ float block_reduce_256(float v, float* red) {
  int tid = threadIdx.x;
  red[tid] = v;
  __syncthreads();
  for (int off = 128; off > 0; off >>= 1) {
    if (tid < off) red[tid] += red[tid + off];
    __syncthreads();
  }
  float r = red[0];
  __syncthreads();
  return r;
}

// ---------------- LayerNorm + gate (one block per row) ----------------
__global__ __launch_bounds__(256) void ln_gate_kernel(const float* __restrict__ hs,
                                                      const float* __restrict__ gw,
                                                      const float* __restrict__ gb,
                                                      const float* __restrict__ lng,
                                                      const float* __restrict__ lnb,
                                                      float* __restrict__ gates) {
  __shared__ float red[256];
  int row = blockIdx.x;
  const float* x = hs + (size_t)row * HDIM;
  float s = 0.f, ss = 0.f;
  for (int i = threadIdx.x * 4; i < HDIM; i += 1024) {
    float4 v = *(const float4*)(x + i);
    s += v.x + v.y + v.z + v.w;
    ss += v.x * v.x + v.y * v.y + v.z * v.z + v.w * v.w;
  }
  s = block_reduce_256(s, red);
  ss = block_reduce_256(ss, red);
  float mean = s * (1.f / HDIM);
  float var = ss * (1.f / HDIM) - mean * mean;
  float rstd = rsqrtf(var + 1e-5f);
  float dot = 0.f;
  for (int i = threadIdx.x * 4; i < HDIM; i += 1024) {
    float4 v = *(const float4*)(x + i);
    float4 g = *(const float4*)(lng + i);
    float4 b = *(const float4*)(lnb + i);
    float4 w = *(const float4*)(gw + i);
    dot += ((v.x - mean) * rstd * g.x + b.x) * w.x;
    dot += ((v.y - mean) * rstd * g.y + b.y) * w.y;
    dot += ((v.z - mean) * rstd * g.z + b.z) * w.z;
    dot += ((v.w - mean) * rstd * g.w + b.w) * w.w;
  }
  dot = block_reduce_256(dot, red);
  if (threadIdx.x == 0) {
    float gi = dot + gb[0];
    gi = fminf(10.f, fmaxf(-10.f, gi));
    gates[row] = 1.f / (1.f + __expf(-gi));
  }
}

// ---------------- regularization loss (single block) -> fp32 scalar ----------------
__global__ __launch_bounds__(256) void reg_loss_kernel(const float* __restrict__ gates,
                                                       float* __restrict__ out) {
  __shared__ float red[256];
  float sb = 0.f, se = 0.f, sg = 0.f;
  for (int i = threadIdx.x; i < S_LEN; i += 256) {
    float g = gates[i];
    float gc = fminf(1.f - 1e-5f, fmaxf(1e-5f, g));
    sb += g * (1.f - g);
    se += g * logf(gc) + (1.f - g) * logf(1.f - gc);
    sg += g;
  }
  sb = block_reduce_256(sb, red);
  se = block_reduce_256(se, red);
  sg = block_reduce_256(sg, red);
  if (threadIdx.x == 0) {
    const float inv = 1.f / (float)S_LEN;
    float reg = -0.1f * (sb * inv) - 0.01f * (se * inv) + 0.1f * (sg * inv);
    out[0] = reg;
  }
}

// ---------------- bf16 GEMM: C(MxN) = A(MxK) * Bt(NxK)^T, all row-major ----------------
// m97 structure: 128x128 tile, BK=32, 4 waves each computing 64x64 via 16x16x32 MFMA.
// OutT = bf16 for intermediates, float for the final projection (d_out is fp32!).
template <typename OutT>
__global__ __launch_bounds__(256) void gemm_bt_kernel(const bf16_t* __restrict__ A,
                                                      const bf16_t* __restrict__ Bt,
                                                      OutT* __restrict__ C,
                                                      int M, int N, int K) {
  __shared__ bf16_t As[128][32];
  __shared__ bf16_t Bs[128][32];
  int tid = threadIdx.x;
  int lane = tid & 63, wave = tid >> 6;
  int wr = wave >> 1, wc = wave & 1;
  int m0 = blockIdx.y * 128, n0 = blockIdx.x * 128;
  int lrow = lane & 15, lhi = lane >> 4;
  f32x4 acc[4][4];
#pragma unroll
  for (int a = 0; a < 4; ++a)
#pragma unroll
    for (int b = 0; b < 4; ++b)
#pragma unroll
      for (int r = 0; r < 4; ++r) acc[a][b][r] = 0.f;

  for (int k0 = 0; k0 < K; k0 += 32) {
    __syncthreads();
#pragma unroll
    for (int i = 0; i < 2; ++i) {
      int c = tid * 2 + i;
      int rr = c >> 2, kk = (c & 3) * 8;
      *(uint4*)(&As[rr][kk]) = *(const uint4*)(A + (size_t)(m0 + rr) * K + k0 + kk);
      *(uint4*)(&Bs[rr][kk]) = *(const uint4*)(Bt + (size_t)(n0 + rr) * K + k0 + kk);
    }
    __syncthreads();
    bf16x8 af[4], bfr[4];
#pragma unroll
    for (int a = 0; a < 4; ++a)
      af[a] = *(const bf16x8*)(&As[wr * 64 + a * 16 + lrow][lhi * 8]);
#pragma unroll
    for (int b = 0; b < 4; ++b)
      bfr[b] = *(const bf16x8*)(&Bs[wc * 64 + b * 16 + lrow][lhi * 8]);
#pragma unroll
    for (int a = 0; a < 4; ++a)
#pragma unroll
      for (int b = 0; b < 4; ++b)
        acc[a][b] = __builtin_amdgcn_mfma_f32_16x16x32_bf16(af[a], bfr[b], acc[a][b], 0, 0, 0);
  }
#pragma unroll
  for (int a = 0; a < 4; ++a)
#pragma unroll
    for (int b = 0; b < 4; ++b)
#pragma unroll
      for (int r = 0; r < 4; ++r) {
        int row = m0 + wr * 64 + a * 16 + lhi * 4 + r;
        int col = n0 + wc * 64 + b * 16 + lrow;
        C[(size_t)row * N + col] = (OutT)acc[a][b][r];
      }
}

// ---------------- dual-softmax flash attention ----------------
// One wave per (head, 16 q-rows). Two online softmaxes (causal-global, +/-64 local band),
// combined by the per-row gate at the end. QKV packed: row s -> [Q(2048) | K(512) | V(512)].
__global__ __launch_bounds__(64) void attn_kernel(const bf16_t* __restrict__ QKV,
                                                  const float* __restrict__ gates,
                                                  bf16_t* __restrict__ out) {
  int h = blockIdx.y, qt = blockIdx.x;
  int q0 = qt * 16;
  int lane = threadIdx.x;
  int lrow = lane & 15, lhi = lane >> 4;
  int hk = h & 3;  // jnp.tile replication: head h -> kv head h % 4
  const bf16_t* Qp = QKV + h * 128;
  const bf16_t* Kp = QKV + 2048 + hk * 128;
  const bf16_t* Vp = QKV + 2560 + hk * 128;

  __shared__ bf16_t Pg[16][32];
  __shared__ bf16_t Pl[16][32];
  __shared__ bf16_t Vs[32][132];  // padded stride: 264B rows, 8B aligned, ~2-way banks

  bf16x8 aq[4];
#pragma unroll
  for (int c = 0; c < 4; ++c)
    aq[c] = *(const bf16x8*)(Qp + (size_t)(q0 + lrow) * QKV_LD + c * 32 + lhi * 8);

  float mg[4], ml[4], lg[4], ll[4];
  f32x4 og[8], ol[8];
#pragma unroll
  for (int r = 0; r < 4; ++r) { mg[r] = ml[r] = -1e30f; lg[r] = ll[r] = 0.f; }
#pragma unroll
  for (int d = 0; d < 8; ++d)
#pragma unroll
    for (int r = 0; r < 4; ++r) { og[d][r] = 0.f; ol[d][r] = 0.f; }

  const float NEGINF = -__builtin_inff();
  const float scl = 0.08838834764831845f;  // 1/sqrt(128)
  int kend = min(S_LEN, q0 + 16 + 64);     // local band reaches q0+15+64

  for (int k0 = 0; k0 < kend; k0 += 32) {
    // ---- scores: 16q x 32k via MFMA, K/Q fragments straight from global ----
    f32x4 sc[2];
#pragma unroll
    for (int t = 0; t < 2; ++t) {
#pragma unroll
      for (int r = 0; r < 4; ++r) sc[t][r] = 0.f;
#pragma unroll
      for (int c = 0; c < 4; ++c) {
        bf16x8 bk = *(const bf16x8*)(Kp + (size_t)(k0 + t * 16 + lrow) * QKV_LD + c * 32 + lhi * 8);
        sc[t] = __builtin_amdgcn_mfma_f32_16x16x32_bf16(aq[c], bk, sc[t], 0, 0, 0);
      }
    }
    __syncthreads();  // previous iter's LDS consumers done before overwrite
    // ---- stage V tile (32 x 128) into LDS, coalesced 8B per lane ----
#pragma unroll
    for (int it = 0; it < 16; ++it) {
      int rr = it * 2 + (lane >> 5);
      int c0 = (lane & 31) * 4;
      *(uint2*)(&Vs[rr][c0]) = *(const uint2*)(Vp + (size_t)(k0 + rr) * QKV_LD + c0);
    }
    // ---- dual online softmax (branchless; -inf masks + m init -1e30 are NaN-safe) ----
#pragma unroll
    for (int r = 0; r < 4; ++r) {
      int i = q0 + lhi * 4 + r;
      float s0 = sc[0][r] * scl, s1 = sc[1][r] * scl;
      int j0 = k0 + lrow, j1 = k0 + 16 + lrow;
      int d0 = i - j0, d1 = i - j1;
      float g0 = (j0 > i) ? NEGINF : s0;
      float g1 = (j1 > i) ? NEGINF : s1;
      float l0 = (d0 > 64 || d0 < -64) ? NEGINF : s0;
      float l1 = (d1 > 64 || d1 < -64) ? NEGINF : s1;
      // global (causal)
      float rmax = fmaxf(g0, g1);
#pragma unroll
      for (int m = 1; m < 16; m <<= 1) rmax = fmaxf(rmax, __shfl_xor(rmax, m, 64));
      float mnew = fmaxf(mg[r], rmax);
      float esc = __expf(mg[r] - mnew);
      float p0 = __expf(g0 - mnew), p1 = __expf(g1 - mnew);
      float ps = p0 + p1;
#pragma unroll
      for (int m = 1; m < 16; m <<= 1) ps += __shfl_xor(ps, m, 64);
      lg[r] = lg[r] * esc + ps;
      mg[r] = mnew;
#pragma unroll
      for (int d = 0; d < 8; ++d) og[d][r] *= esc;
      Pg[lhi * 4 + r][lrow] = (bf16_t)p0;
      Pg[lhi * 4 + r][16 + lrow] = (bf16_t)p1;
      // local (symmetric band)
      rmax = fmaxf(l0, l1);
#pragma unroll
      for (int m = 1; m < 16; m <<= 1) rmax = fmaxf(rmax, __shfl_xor(rmax, m, 64));
      mnew = fmaxf(ml[r], rmax);
      esc = __expf(ml[r] - mnew);
      p0 = __expf(l0 - mnew); p1 = __expf(l1 - mnew);
      ps = p0 + p1;
#pragma unroll
      for (int m = 1; m < 16; m <<= 1) ps += __shfl_xor(ps, m, 64);
      ll[r] = ll[r] * esc + ps;
      ml[r] = mnew;
#pragma unroll
      for (int d = 0; d < 8; ++d) ol[d][r] *= esc;
      Pl[lhi * 4 + r][lrow] = (bf16_t)p0;
      Pl[lhi * 4 + r][16 + lrow] = (bf16_t)p1;
    }
    __syncthreads();
    // ---- PV: O(16x128) += P(16x32) @ V(32x128), both softmax branches ----
    bf16x8 apg = *(const bf16x8*)(&Pg[lrow][lhi * 8]);
    bf16x8 apl = *(const bf16x8*)(&Pl[lrow][lhi * 8]);
#pragma unroll
    for (int d = 0; d < 8; ++d) {
      bf16x8 bv;
#pragma unroll
      for (int j = 0; j < 8; ++j) bv[j] = Vs[lhi * 8 + j][d * 16 + lrow];
      og[d] = __builtin_amdgcn_mfma_f32_16x16x32_bf16(apg, bv, og[d], 0, 0, 0);
      ol[d] = __builtin_amdgcn_mfma_f32_16x16x32_bf16(apl, bv, ol[d], 0, 0, 0);
    }
  }
  // ---- gate-combine and write attn_out (bf16, [S][2048]) ----
#pragma unroll
  for (int r = 0; r < 4; ++r) {
    int i = q0 + lhi * 4 + r;
    float gv = gates[i];
    float il = 1.f / ll[r], ig = 1.f / lg[r];
#pragma unroll
    for (int d = 0; d < 8; ++d)
      out[(size_t)i * HDIM + h * 128 + d * 16 + lrow] =
          (bf16_t)(gv * ol[d][r] * il + (1.f - gv) * og[d][r] * ig);
  }
}

// ---------------- launch ----------------
extern "C" void kernel_launch(void* const* d_in, const int* in_sizes, int n_in,
                              void* d_out, int out_size, void* d_ws, size_t ws_size,
                              hipStream_t stream) {
  const float* hs  = (const float*)d_in[0];
  const float* Wq  = (const float*)d_in[1];
  const float* Wk  = (const float*)d_in[2];
  const float* Wv  = (const float*)d_in[3];
  const float* Wo  = (const float*)d_in[4];
  const float* gw  = (const float*)d_in[5];
  const float* gb  = (const float*)d_in[6];
  const float* lng = (const float*)d_in[7];
  const float* lnb = (const float*)d_in[8];
  float* out = (float*)d_out;  // reference output dtype is float32!

  char* ws = (char*)d_ws;
  bf16_t* hsb   = (bf16_t*)(ws);                    // 2048x2048 bf16 = 8 MB
  bf16_t* wt    = (bf16_t*)(ws + 8388608);          // 3072x2048 bf16 (Wq^T|Wk^T|Wv^T) = 12 MB
  bf16_t* wot   = (bf16_t*)(ws + 20971520);         // 2048x2048 bf16 = 8 MB
  bf16_t* qkv   = (bf16_t*)(ws + 29360128);         // 2048x3072 bf16 = 12 MB
  bf16_t* ao    = (bf16_t*)(ws + 41943040);         // 2048x2048 bf16 = 8 MB
  float*  gates = (float*)(ws + 50331648);          // 2048 fp32

  // casts / transposes
  cast_bf16_kernel<<<4096, 256, 0, stream>>>(hs, hsb, 1048576);
  transpose_cast_kernel<<<dim3(64, 64), 256, 0, stream>>>(Wq, wt, 2048, 2048);
  transpose_cast_kernel<<<dim3(16, 64), 256, 0, stream>>>(Wk, wt + (size_t)2048 * 2048, 2048, 512);
  transpose_cast_kernel<<<dim3(16, 64), 256, 0, stream>>>(Wv, wt + (size_t)2560 * 2048, 2048, 512);
  transpose_cast_kernel<<<dim3(64, 64), 256, 0, stream>>>(Wo, wot, 2048, 2048);

  // gates + reg loss (reg scalar is output element 4194304, fp32)
  ln_gate_kernel<<<2048, 256, 0, stream>>>(hs, gw, gb, lng, lnb, gates);
  reg_loss_kernel<<<1, 256, 0, stream>>>(gates, out + (size_t)4194304);

  // fused QKV projection: [S,2048] x [2048,3072] -> [S,3072] (bf16)
  gemm_bt_kernel<bf16_t><<<dim3(24, 16), 256, 0, stream>>>(hsb, wt, qkv, 2048, 3072, 2048);

  // attention
  attn_kernel<<<dim3(128, 16), 64, 0, stream>>>(qkv, gates, ao);

  // output projection -> d_out (fp32)
  gemm_bt_kernel<float><<<dim3(16, 16), 256, 0, stream>>>(ao, wot, out, 2048, 2048, 2048);
}

// Round 3
// 268.868 us; speedup vs baseline: 1.4654x; 1.4654x over previous
//
#include <hip/hip_runtime.h>
#include <hip/hip_bf16.h>
#include <math.h>

typedef __bf16 bf16_t;
typedef bf16_t bf16x8 __attribute__((ext_vector_type(8)));
typedef bf16_t bf16x4v __attribute__((ext_vector_type(4)));
typedef float f32x4 __attribute__((ext_vector_type(4)));

#define S_LEN 2048
#define HDIM 2048
#define QKV_LD 3072

// ---------------- cast fp32 -> bf16 (vectorized) ----------------
__global__ __launch_bounds__(256) void cast_bf16_kernel(const float* __restrict__ in,
                                                        bf16_t* __restrict__ out, int n4) {
  int i = blockIdx.x * 256 + threadIdx.x;
  if (i >= n4) return;
  float4 v = ((const float4*)in)[i];
  bf16x4v o;
  o[0] = (bf16_t)v.x; o[1] = (bf16_t)v.y; o[2] = (bf16_t)v.z; o[3] = (bf16_t)v.w;
  ((bf16x4v*)out)[i] = o;
}

// ---------------- transpose + cast: in (K x N) fp32 -> out (N x K) bf16 ----------------
__global__ __launch_bounds__(256) void transpose_cast_kernel(const float* __restrict__ in,
                                                             bf16_t* __restrict__ out,
                                                             int K, int N) {
  __shared__ float tile[32][33];
  int n0 = blockIdx.x * 32, k0 = blockIdx.y * 32;
  int tx = threadIdx.x & 31, ty = threadIdx.x >> 5;
#pragma unroll
  for (int i = 0; i < 4; ++i)
    tile[ty + i * 8][tx] = in[(size_t)(k0 + ty + i * 8) * N + n0 + tx];
  __syncthreads();
#pragma unroll
  for (int i = 0; i < 4; ++i)
    out[(size_t)(n0 + ty + i * 8) * K + k0 + tx] = (bf16_t)tile[tx][ty + i * 8];
}

// ---------------- block reduction helper (blockDim == 256) ----------------
__device__ __forceinline__ float block_reduce_256(float v, float* red) {
  int tid = threadIdx.x;
  red[tid] = v;
  __syncthreads();
  for (int off = 128; off > 0; off >>= 1) {
    if (tid < off) red[tid] += red[tid + off];
    __syncthreads();
  }
  float r = red[0];
  __syncthreads();
  return r;
}

// ---------------- LayerNorm + gate (one block per row) ----------------
__global__ __launch_bounds__(256) void ln_gate_kernel(const float* __restrict__ hs,
                                                      const float* __restrict__ gw,
                                                      const float* __restrict__ gb,
                                                      const float* __restrict__ lng,
                                                      const float* __restrict__ lnb,
                                                      float* __restrict__ gates) {
  __shared__ float red[256];
  int row = blockIdx.x;
  const float* x = hs + (size_t)row * HDIM;
  float s = 0.f, ss = 0.f;
  for (int i = threadIdx.x * 4; i < HDIM; i += 1024) {
    float4 v = *(const float4*)(x + i);
    s += v.x + v.y + v.z + v.w;
    ss += v.x * v.x + v.y * v.y + v.z * v.z + v.w * v.w;
  }
  s = block_reduce_256(s, red);
  ss = block_reduce_256(ss, red);
  float mean = s * (1.f / HDIM);
  float var = ss * (1.f / HDIM) - mean * mean;
  float rstd = rsqrtf(var + 1e-5f);
  float dot = 0.f;
  for (int i = threadIdx.x * 4; i < HDIM; i += 1024) {
    float4 v = *(const float4*)(x + i);
    float4 g = *(const float4*)(lng + i);
    float4 b = *(const float4*)(lnb + i);
    float4 w = *(const float4*)(gw + i);
    dot += ((v.x - mean) * rstd * g.x + b.x) * w.x;
    dot += ((v.y - mean) * rstd * g.y + b.y) * w.y;
    dot += ((v.z - mean) * rstd * g.z + b.z) * w.z;
    dot += ((v.w - mean) * rstd * g.w + b.w) * w.w;
  }
  dot = block_reduce_256(dot, red);
  if (threadIdx.x == 0) {
    float gi = dot + gb[0];
    gi = fminf(10.f, fmaxf(-10.f, gi));
    gates[row] = 1.f / (1.f + __expf(-gi));
  }
}

// ---------------- regularization loss (single block) -> fp32 scalar ----------------
__global__ __launch_bounds__(256) void reg_loss_kernel(const float* __restrict__ gates,
                                                       float* __restrict__ out) {
  __shared__ float red[256];
  float sb = 0.f, se = 0.f, sg = 0.f;
  for (int i = threadIdx.x; i < S_LEN; i += 256) {
    float g = gates[i];
    float gc = fminf(1.f - 1e-5f, fmaxf(1e-5f, g));
    sb += g * (1.f - g);
    se += g * logf(gc) + (1.f - g) * logf(1.f - gc);
    sg += g;
  }
  sb = block_reduce_256(sb, red);
  se = block_reduce_256(se, red);
  sg = block_reduce_256(sg, red);
  if (threadIdx.x == 0) {
    const float inv = 1.f / (float)S_LEN;
    float reg = -0.1f * (sb * inv) - 0.01f * (se * inv) + 0.1f * (sg * inv);
    out[0] = reg;
  }
}

// ---------------- bf16 GEMM: C(MxN) = A(MxK) * Bt(NxK)^T, all row-major ----------------
template <typename OutT>
__global__ __launch_bounds__(256) void gemm_bt_kernel(const bf16_t* __restrict__ A,
                                                      const bf16_t* __restrict__ Bt,
                                                      OutT* __restrict__ C,
                                                      int M, int N, int K) {
  __shared__ bf16_t As[128][32];
  __shared__ bf16_t Bs[128][32];
  int tid = threadIdx.x;
  int lane = tid & 63, wave = tid >> 6;
  int wr = wave >> 1, wc = wave & 1;
  int m0 = blockIdx.y * 128, n0 = blockIdx.x * 128;
  int lrow = lane & 15, lhi = lane >> 4;
  f32x4 acc[4][4];
#pragma unroll
  for (int a = 0; a < 4; ++a)
#pragma unroll
    for (int b = 0; b < 4; ++b)
#pragma unroll
      for (int r = 0; r < 4; ++r) acc[a][b][r] = 0.f;

  for (int k0 = 0; k0 < K; k0 += 32) {
    __syncthreads();
#pragma unroll
    for (int i = 0; i < 2; ++i) {
      int c = tid * 2 + i;
      int rr = c >> 2, kk = (c & 3) * 8;
      *(uint4*)(&As[rr][kk]) = *(const uint4*)(A + (size_t)(m0 + rr) * K + k0 + kk);
      *(uint4*)(&Bs[rr][kk]) = *(const uint4*)(Bt + (size_t)(n0 + rr) * K + k0 + kk);
    }
    __syncthreads();
    bf16x8 af[4], bfr[4];
#pragma unroll
    for (int a = 0; a < 4; ++a)
      af[a] = *(const bf16x8*)(&As[wr * 64 + a * 16 + lrow][lhi * 8]);
#pragma unroll
    for (int b = 0; b < 4; ++b)
      bfr[b] = *(const bf16x8*)(&Bs[wc * 64 + b * 16 + lrow][lhi * 8]);
#pragma unroll
    for (int a = 0; a < 4; ++a)
#pragma unroll
      for (int b = 0; b < 4; ++b)
        acc[a][b] = __builtin_amdgcn_mfma_f32_16x16x32_bf16(af[a], bfr[b], acc[a][b], 0, 0, 0);
  }
#pragma unroll
  for (int a = 0; a < 4; ++a)
#pragma unroll
    for (int b = 0; b < 4; ++b)
#pragma unroll
      for (int r = 0; r < 4; ++r) {
        int row = m0 + wr * 64 + a * 16 + lhi * 4 + r;
        int col = n0 + wc * 64 + b * 16 + lrow;
        C[(size_t)row * N + col] = (OutT)acc[a][b][r];
      }
}

// ---------------- dual-softmax flash attention v2 ----------------
// Block = 256 threads (4 waves) x (head, 64-row q-chunk). Wave w owns rows
// [q0c+16w, +16). 64-key iterations; K tile [64][128] XOR-swizzled in LDS,
// V tile transposed [128][72] in LDS (in-reg transpose, b64 writes).
// Global-causal branch skipped past the diagonal; local band branch only on
// the <=3 tiles intersecting |i-j|<=64. Chunk pairing c<->31-c balances load.
__global__ __launch_bounds__(256, 2) void attn_kernel(const bf16_t* __restrict__ QKV,
                                                      const float* __restrict__ gates,
                                                      bf16_t* __restrict__ out) {
  __shared__ bf16_t Ks[2][64][128];   // 32 KB, chunk-swizzled: chunk ^= row&7
  __shared__ bf16_t Vt[2][128][72];   // 36 KB, V^T, padded stride
  __shared__ bf16_t Pw[4][16][72];    // 9 KB, per-wave P (shared g/l, sequential)

  int b = blockIdx.x;
  int h = b & 15;
  int t5 = b >> 4;                       // 0..31
  int c = (t5 < 16) ? (31 - t5) : (t5 - 16);  // pair c with 31-c on same CU
  int q0c = c * 64;
  int tid = threadIdx.x;
  int lane = tid & 63, w = tid >> 6;
  int lrow = lane & 15, lhi = lane >> 4;
  int q0w = q0c + w * 16;
  int hk = h & 3;
  const bf16_t* Qp = QKV + h * 128;
  const bf16_t* Kp = QKV + 2048 + hk * 128;
  const bf16_t* Vp = QKV + 2560 + hk * 128;

  // Q A-fragments (row = lrow, contraction chunk = lhi*8 + 32*ks)
  bf16x8 aq[4];
#pragma unroll
  for (int ks = 0; ks < 4; ++ks)
    aq[ks] = *(const bf16x8*)(Qp + (size_t)(q0w + lrow) * QKV_LD + ks * 32 + lhi * 8);

  float mg[4], ml[4], lg[4], ll[4];
  f32x4 og[8], ol[8];
#pragma unroll
  for (int r = 0; r < 4; ++r) { mg[r] = ml[r] = -1e30f; lg[r] = ll[r] = 0.f; }
#pragma unroll
  for (int d = 0; d < 8; ++d)
#pragma unroll
    for (int r = 0; r < 4; ++r) { og[d][r] = 0.f; ol[d][r] = 0.f; }

  const float NEGINF = -__builtin_inff();
  const float scl = 0.08838834764831845f;  // 1/sqrt(128)
  int kend = q0c + 128;
  if (kend > S_LEN) kend = S_LEN;
  int nt = kend >> 6;

  // staging thread mapping
  int kr = tid >> 4, c16 = tid & 15;      // K: row kr(+16i), 16B chunk c16
  int vkq = tid >> 4, vdg = tid & 15;     // V: k-quad base 4*vkq(+16i rows? no: rows 4vkq+jj), d-chunk vdg

  // ---- prologue: stage tile 0 into buffer 0 ----
  {
    bf16x8 kreg[4], vreg[4];
#pragma unroll
    for (int i = 0; i < 4; ++i)
      kreg[i] = *(const bf16x8*)(Kp + (size_t)(kr + i * 16) * QKV_LD + c16 * 8);
#pragma unroll
    for (int jj = 0; jj < 4; ++jj)
      vreg[jj] = *(const bf16x8*)(Vp + (size_t)(vkq * 4 + jj) * QKV_LD + vdg * 8);
#pragma unroll
    for (int i = 0; i < 4; ++i) {
      int rr = kr + i * 16;
      *(bf16x8*)(&Ks[0][rr][(c16 ^ (rr & 7)) * 8]) = kreg[i];
    }
#pragma unroll
    for (int e = 0; e < 8; ++e) {
      bf16x4v q;
      q[0] = vreg[0][e]; q[1] = vreg[1][e]; q[2] = vreg[2][e]; q[3] = vreg[3][e];
      *(bf16x4v*)(&Vt[0][vdg * 8 + e][vkq * 4]) = q;
    }
  }
  __syncthreads();

  for (int ti = 0; ti < nt; ++ti) {
    int k0 = ti << 6;
    int bufc = ti & 1, bufn = bufc ^ 1;
    bool more = (ti + 1 < nt);

    // ---- issue next tile's global loads early (hide under compute) ----
    bf16x8 kreg[4], vreg[4];
    if (more) {
      int k0n = k0 + 64;
#pragma unroll
      for (int i = 0; i < 4; ++i)
        kreg[i] = *(const bf16x8*)(Kp + (size_t)(k0n + kr + i * 16) * QKV_LD + c16 * 8);
#pragma unroll
      for (int jj = 0; jj < 4; ++jj)
        vreg[jj] = *(const bf16x8*)(Vp + (size_t)(k0n + vkq * 4 + jj) * QKV_LD + vdg * 8);
    }

    // ---- QK^T: 16q x 64k per wave ----
    f32x4 sc[4];
#pragma unroll
    for (int t = 0; t < 4; ++t) {
#pragma unroll
      for (int r = 0; r < 4; ++r) sc[t][r] = 0.f;
    }
#pragma unroll
    for (int t = 0; t < 4; ++t) {
      int n = t * 16 + lrow;
      int swz = (n & 7);
#pragma unroll
      for (int ks = 0; ks < 4; ++ks) {
        bf16x8 bk = *(const bf16x8*)(&Ks[bufc][n][((ks * 4 + lhi) ^ swz) * 8]);
        sc[t] = __builtin_amdgcn_mfma_f32_16x16x32_bf16(aq[ks], bk, sc[t], 0, 0, 0);
      }
    }

    // wave-level branch activity
    bool g_act = (k0 <= q0w + 15);
    bool g_full = (k0 + 63 <= q0w);
    bool l_act = (k0 + 63 >= q0w - 64) && (k0 <= q0w + 79);

    // ---- global (causal) branch ----
    if (g_act) {
#pragma unroll
      for (int r = 0; r < 4; ++r) {
        int i = q0w + lhi * 4 + r;
        float v0, v1, v2, v3;
        if (g_full) {
          v0 = sc[0][r] * scl; v1 = sc[1][r] * scl;
          v2 = sc[2][r] * scl; v3 = sc[3][r] * scl;
        } else {
          int j = k0 + lrow;
          v0 = (j > i) ? NEGINF : sc[0][r] * scl;
          v1 = (j + 16 > i) ? NEGINF : sc[1][r] * scl;
          v2 = (j + 32 > i) ? NEGINF : sc[2][r] * scl;
          v3 = (j + 48 > i) ? NEGINF : sc[3][r] * scl;
        }
        float rmax = fmaxf(fmaxf(v0, v1), fmaxf(v2, v3));
#pragma unroll
        for (int m = 1; m < 16; m <<= 1) rmax = fmaxf(rmax, __shfl_xor(rmax, m, 64));
        float mnew = fmaxf(mg[r], rmax);
        float esc = __expf(mg[r] - mnew);
        float p0 = __expf(v0 - mnew), p1 = __expf(v1 - mnew);
        float p2 = __expf(v2 - mnew), p3 = __expf(v3 - mnew);
        int pr = lhi * 4 + r;
        Pw[w][pr][lrow] = (bf16_t)p0;
        Pw[w][pr][16 + lrow] = (bf16_t)p1;
        Pw[w][pr][32 + lrow] = (bf16_t)p2;
        Pw[w][pr][48 + lrow] = (bf16_t)p3;
        float ps = (p0 + p1) + (p2 + p3);
#pragma unroll
        for (int m = 1; m < 16; m <<= 1) ps += __shfl_xor(ps, m, 64);
        lg[r] = lg[r] * esc + ps;
        mg[r] = mnew;
#pragma unroll
        for (int d = 0; d < 8; ++d) og[d][r] *= esc;
      }
      bf16x8 ap0 = *(const bf16x8*)(&Pw[w][lrow][lhi * 8]);
      bf16x8 ap1 = *(const bf16x8*)(&Pw[w][lrow][32 + lhi * 8]);
#pragma unroll
      for (int d = 0; d < 8; ++d) {
        int drow = d * 16 + lrow;
        bf16x8 bv0 = *(const bf16x8*)(&Vt[bufc][drow][lhi * 8]);
        bf16x8 bv1 = *(const bf16x8*)(&Vt[bufc][drow][32 + lhi * 8]);
        og[d] = __builtin_amdgcn_mfma_f32_16x16x32_bf16(ap0, bv0, og[d], 0, 0, 0);
        og[d] = __builtin_amdgcn_mfma_f32_16x16x32_bf16(ap1, bv1, og[d], 0, 0, 0);
      }
    }

    // ---- local (band) branch: only ~3 tiles per wave ----
    if (l_act) {
#pragma unroll
      for (int r = 0; r < 4; ++r) {
        int i = q0w + lhi * 4 + r;
        int j = k0 + lrow;
        int d0 = i - j, d1 = d0 - 16, d2 = d0 - 32, d3 = d0 - 48;
        float v0 = (d0 > 64 || d0 < -64) ? NEGINF : sc[0][r] * scl;
        float v1 = (d1 > 64 || d1 < -64) ? NEGINF : sc[1][r] * scl;
        float v2 = (d2 > 64 || d2 < -64) ? NEGINF : sc[2][r] * scl;
        float v3 = (d3 > 64 || d3 < -64) ? NEGINF : sc[3][r] * scl;
        float rmax = fmaxf(fmaxf(v0, v1), fmaxf(v2, v3));
#pragma unroll
        for (int m = 1; m < 16; m <<= 1) rmax = fmaxf(rmax, __shfl_xor(rmax, m, 64));
        float mnew = fmaxf(ml[r], rmax);
        float esc = __expf(ml[r] - mnew);
        float p0 = __expf(v0 - mnew), p1 = __expf(v1 - mnew);
        float p2 = __expf(v2 - mnew), p3 = __expf(v3 - mnew);
        int pr = lhi * 4 + r;
        Pw[w][pr][lrow] = (bf16_t)p0;
        Pw[w][pr][16 + lrow] = (bf16_t)p1;
        Pw[w][pr][32 + lrow] = (bf16_t)p2;
        Pw[w][pr][48 + lrow] = (bf16_t)p3;
        float ps = (p0 + p1) + (p2 + p3);
#pragma unroll
        for (int m = 1; m < 16; m <<= 1) ps += __shfl_xor(ps, m, 64);
        ll[r] = ll[r] * esc + ps;
        ml[r] = mnew;
#pragma unroll
        for (int d = 0; d < 8; ++d) ol[d][r] *= esc;
      }
      bf16x8 ap0 = *(const bf16x8*)(&Pw[w][lrow][lhi * 8]);
      bf16x8 ap1 = *(const bf16x8*)(&Pw[w][lrow][32 + lhi * 8]);
#pragma unroll
      for (int d = 0; d < 8; ++d) {
        int drow = d * 16 + lrow;
        bf16x8 bv0 = *(const bf16x8*)(&Vt[bufc][drow][lhi * 8]);
        bf16x8 bv1 = *(const bf16x8*)(&Vt[bufc][drow][32 + lhi * 8]);
        ol[d] = __builtin_amdgcn_mfma_f32_16x16x32_bf16(ap0, bv0, ol[d], 0, 0, 0);
        ol[d] = __builtin_amdgcn_mfma_f32_16x16x32_bf16(ap1, bv1, ol[d], 0, 0, 0);
      }
    }

    // ---- write next tile into the other buffer, then fence ----
    if (more) {
#pragma unroll
      for (int i = 0; i < 4; ++i) {
        int rr = kr + i * 16;
        *(bf16x8*)(&Ks[bufn][rr][(c16 ^ (rr & 7)) * 8]) = kreg[i];
      }
#pragma unroll
      for (int e = 0; e < 8; ++e) {
        bf16x4v q;
        q[0] = vreg[0][e]; q[1] = vreg[1][e]; q[2] = vreg[2][e]; q[3] = vreg[3][e];
        *(bf16x4v*)(&Vt[bufn][vdg * 8 + e][vkq * 4]) = q;
      }
    }
    __syncthreads();
  }

  // ---- gate-combine and write attn_out (bf16, [S][2048]) ----
#pragma unroll
  for (int r = 0; r < 4; ++r) {
    int i = q0w + lhi * 4 + r;
    float gv = gates[i];
    float il = 1.f / ll[r], ig = 1.f / lg[r];
#pragma unroll
    for (int d = 0; d < 8; ++d)
      out[(size_t)i * HDIM + h * 128 + d * 16 + lrow] =
          (bf16_t)(gv * ol[d][r] * il + (1.f - gv) * og[d][r] * ig);
  }
}

// ---------------- launch ----------------
extern "C" void kernel_launch(void* const* d_in, const int* in_sizes, int n_in,
                              void* d_out, int out_size, void* d_ws, size_t ws_size,
                              hipStream_t stream) {
  const float* hs  = (const float*)d_in[0];
  const float* Wq  = (const float*)d_in[1];
  const float* Wk  = (const float*)d_in[2];
  const float* Wv  = (const float*)d_in[3];
  const float* Wo  = (const float*)d_in[4];
  const float* gw  = (const float*)d_in[5];
  const float* gb  = (const float*)d_in[6];
  const float* lng = (const float*)d_in[7];
  const float* lnb = (const float*)d_in[8];
  float* out = (float*)d_out;  // reference output dtype is float32

  char* ws = (char*)d_ws;
  bf16_t* hsb   = (bf16_t*)(ws);                    // 2048x2048 bf16 = 8 MB
  bf16_t* wt    = (bf16_t*)(ws + 8388608);          // 3072x2048 bf16 (Wq^T|Wk^T|Wv^T) = 12 MB
  bf16_t* wot   = (bf16_t*)(ws + 20971520);         // 2048x2048 bf16 = 8 MB
  bf16_t* qkv   = (bf16_t*)(ws + 29360128);         // 2048x3072 bf16 = 12 MB
  bf16_t* ao    = (bf16_t*)(ws + 41943040);         // 2048x2048 bf16 = 8 MB
  float*  gates = (float*)(ws + 50331648);          // 2048 fp32

  cast_bf16_kernel<<<4096, 256, 0, stream>>>(hs, hsb, 1048576);
  transpose_cast_kernel<<<dim3(64, 64), 256, 0, stream>>>(Wq, wt, 2048, 2048);
  transpose_cast_kernel<<<dim3(16, 64), 256, 0, stream>>>(Wk, wt + (size_t)2048 * 2048, 2048, 512);
  transpose_cast_kernel<<<dim3(16, 64), 256, 0, stream>>>(Wv, wt + (size_t)2560 * 2048, 2048, 512);
  transpose_cast_kernel<<<dim3(64, 64), 256, 0, stream>>>(Wo, wot, 2048, 2048);

  ln_gate_kernel<<<2048, 256, 0, stream>>>(hs, gw, gb, lng, lnb, gates);
  reg_loss_kernel<<<1, 256, 0, stream>>>(gates, out + (size_t)4194304);

  // fused QKV projection: [S,2048] x [2048,3072] -> [S,3072] (bf16)
  gemm_bt_kernel<bf16_t><<<dim3(24, 16), 256, 0, stream>>>(hsb, wt, qkv, 2048, 3072, 2048);

  // attention: 512 blocks = 32 chunk-slots x 16 heads, 4 waves each
  attn_kernel<<<dim3(512), 256, 0, stream>>>(qkv, gates, ao);

  // output projection -> d_out (fp32)
  gemm_bt_kernel<float><<<dim3(16, 16), 256, 0, stream>>>(ao, wot, out, 2048, 2048, 2048);
}